// Round 9
// baseline (855.762 us; speedup 1.0000x reference)
//
#include <hip/hip_runtime.h>
#include <float.h>

#define BATCH 8
#define SEQ   1024
#define CDIM  512
#define HEADS 8
#define HD    64
#define TOPK  16
#define MTOT  (BATCH*SEQ)                     // 8192
#define HSZ   ((size_t)BATCH*HEADS*SEQ*HD)    // 4194304
#define XPLANE  ((size_t)MTOT*CDIM)           // 4194304
#define WTPLANE ((size_t)3*CDIM*CDIM)         // 786432  (1536x512)
#define WPPLANE ((size_t)CDIM*CDIM)           // 262144  (512x512)

typedef short bf16x8 __attribute__((ext_vector_type(8)));
typedef float f32x4v __attribute__((ext_vector_type(4)));
typedef unsigned short u16;

#define MFMA16(a,b,c) __builtin_amdgcn_mfma_f32_16x16x32_bf16((a),(b),(c),0,0,0)

// round-to-nearest bf16 split: f = hi + lo, each bf16; |err| ~ 2^-17 |f|
__device__ inline void bf16split(float f, u16& h, u16& l) {
    unsigned u = __float_as_uint(f);
    unsigned hr = (u + 0x7fffu + ((u >> 16) & 1u)) >> 16;
    h = (u16)hr;
    float rest = f - __uint_as_float(hr << 16);
    unsigned v = __float_as_uint(rest);
    l = (u16)((v + 0x7fffu + ((v >> 16) & 1u)) >> 16);
}

__device__ inline void bf16split4(float4 f, ushort4& h, ushort4& l) {
    bf16split(f.x, h.x, l.x); bf16split(f.y, h.y, l.y);
    bf16split(f.z, h.z, l.z); bf16split(f.w, h.w, l.w);
}

// ============================================================
// Prep 1: elementwise split fp32 -> bf16 hi/lo planes
// ============================================================
__global__ __launch_bounds__(256) void split_f32_kernel(
    const float* __restrict__ in, u16* __restrict__ hi, u16* __restrict__ lo, int n4)
{
    int i = blockIdx.x * 256 + threadIdx.x;
    if (i < n4) {
        float4 f = ((const float4*)in)[i];
        ushort4 h, l; bf16split4(f, h, l);
        ((ushort4*)hi)[i] = h; ((ushort4*)lo)[i] = l;
    }
}

// ============================================================
// Prep 2: transpose + split.  W:[512][ncols] fp32 -> out:[ncols][512] hi/lo
// ============================================================
__global__ __launch_bounds__(256) void tsplit_kernel(
    const float* __restrict__ W, int ncols, u16* __restrict__ ohi, u16* __restrict__ olo)
{
    __shared__ float t_s[64][65];
    const int tid = threadIdx.x, tx = tid & 15, ty = tid >> 4;
    const int cb = blockIdx.x * 64, kb = blockIdx.y * 64;
    #pragma unroll
    for (int i = 0; i < 4; i++)
        *(float4*)&t_s[ty*4+i][tx*4] =
            *(const float4*)(W + (size_t)(kb + ty*4 + i) * ncols + cb + tx*4);
    __syncthreads();
    #pragma unroll
    for (int i = 0; i < 4; i++) {
        int rr = ty*4 + i;
        float4 f;
        f.x = t_s[tx*4+0][rr]; f.y = t_s[tx*4+1][rr];
        f.z = t_s[tx*4+2][rr]; f.w = t_s[tx*4+3][rr];
        ushort4 h, l; bf16split4(f, h, l);
        *(ushort4*)(ohi + (size_t)(cb + rr) * 512 + kb + tx*4) = h;
        *(ushort4*)(olo + (size_t)(cb + rr) * 512 + kb + tx*4) = l;
    }
}

// ============================================================
// Kernel 1: QKV projection, split-bf16 MFMA, ZERO LDS / ZERO barriers.
// Block = 128 rows x 64 cols; wave = 32 rows x 64 cols. Grid (64,24)
// = 1536 blocks = 6 blocks/CU (TLP). Fragments direct from global
// planes. Epilogue: bias; q: relu*0.125; scatter scalar stores.
// ============================================================
__global__ __launch_bounds__(256) void qkv_mfma_kernel(
    const u16* __restrict__ xpl,      // [2][8192][512]
    const u16* __restrict__ wtpl,     // [2][1536][512]
    const float* __restrict__ bq, const float* __restrict__ bkv,
    u16* __restrict__ qhi_g, u16* __restrict__ qlo_g,
    u16* __restrict__ khi_g, u16* __restrict__ klo_g,
    float* __restrict__ v_ws)
{
    const int tid = threadIdx.x, lane = tid & 63, w = tid >> 6;
    const int l15 = lane & 15, l4 = lane >> 4;
    const int row0 = blockIdx.x * 128 + w * 32;
    const int cblk = blockIdx.y;          // 0..23: 0-7 q, 8-15 k, 16-23 v
    const int c0 = cblk * 64;

    f32x4v acc[2][4];
    #pragma unroll
    for (int rt = 0; rt < 2; rt++)
        #pragma unroll
        for (int nt = 0; nt < 4; nt++) acc[rt][nt] = (f32x4v){0.f,0.f,0.f,0.f};

    const u16* aph = xpl  + (size_t)(row0 + l15) * 512 + l4 * 8;
    const u16* bph = wtpl + (size_t)(c0   + l15) * 512 + l4 * 8;

    #pragma unroll 2
    for (int kc = 0; kc < 16; kc++) {
        const int ko = kc * 32;
        bf16x8 a0h = *(const bf16x8*)(aph + ko);
        bf16x8 a0l = *(const bf16x8*)(aph + XPLANE + ko);
        bf16x8 a1h = *(const bf16x8*)(aph + 16*512 + ko);
        bf16x8 a1l = *(const bf16x8*)(aph + XPLANE + 16*512 + ko);
        #pragma unroll
        for (int nt = 0; nt < 4; nt++) {
            bf16x8 bh_ = *(const bf16x8*)(bph + nt*16*512 + ko);
            bf16x8 bl_ = *(const bf16x8*)(bph + WTPLANE + nt*16*512 + ko);
            acc[0][nt] = MFMA16(a0h, bh_, acc[0][nt]);
            acc[0][nt] = MFMA16(a0h, bl_, acc[0][nt]);
            acc[0][nt] = MFMA16(a0l, bh_, acc[0][nt]);
            acc[1][nt] = MFMA16(a1h, bh_, acc[1][nt]);
            acc[1][nt] = MFMA16(a1h, bl_, acc[1][nt]);
            acc[1][nt] = MFMA16(a1l, bh_, acc[1][nt]);
        }
    }

    const int rbase = row0 + l4 * 4;
    if (cblk < 8) {
        #pragma unroll
        for (int nt = 0; nt < 4; nt++) {
            const int cg = c0 + nt*16 + l15;          // 0..511
            const int h = cg >> 6, d = cg & 63;
            const float bias = bq[cg];
            #pragma unroll
            for (int rt = 0; rt < 2; rt++)
                #pragma unroll
                for (int rg = 0; rg < 4; rg++) {
                    int r = rbase + rt*16 + rg;
                    int bb = r >> 10, nn = r & (SEQ - 1);
                    float f = fmaxf(acc[rt][nt][rg] + bias, 0.f) * 0.125f;
                    u16 hh, ll; bf16split(f, hh, ll);
                    size_t base = (((size_t)(bb*HEADS + h)) << 16) + ((size_t)nn << 6) + d;
                    qhi_g[base] = hh; qlo_g[base] = ll;
                }
        }
    } else if (cblk < 16) {
        #pragma unroll
        for (int nt = 0; nt < 4; nt++) {
            const int c2 = c0 - CDIM + nt*16 + l15;   // 0..511
            const int h = c2 >> 6, d = c2 & 63;
            const float bias = bkv[c2];
            #pragma unroll
            for (int rt = 0; rt < 2; rt++)
                #pragma unroll
                for (int rg = 0; rg < 4; rg++) {
                    int r = rbase + rt*16 + rg;
                    int bb = r >> 10, nn = r & (SEQ - 1);
                    float f = acc[rt][nt][rg] + bias;
                    u16 hh, ll; bf16split(f, hh, ll);
                    size_t base = (((size_t)(bb*HEADS + h)) << 16) + ((size_t)nn << 6) + d;
                    khi_g[base] = hh; klo_g[base] = ll;
                }
        }
    } else {
        #pragma unroll
        for (int nt = 0; nt < 4; nt++) {
            const int c3 = c0 - 2*CDIM + nt*16 + l15; // 0..511
            const int h = c3 >> 6, d = c3 & 63;
            const float bias = bkv[CDIM + c3];
            #pragma unroll
            for (int rt = 0; rt < 2; rt++)
                #pragma unroll
                for (int rg = 0; rg < 4; rg++) {
                    int r = rbase + rt*16 + rg;
                    int bb = r >> 10, nn = r & (SEQ - 1);
                    size_t base = (((size_t)(bb*HEADS + h)) << 16) + ((size_t)nn << 6) + d;
                    v_ws[base] = acc[rt][nt][rg] + bias;
                }
        }
    }
}

// ============================================================
// Kernel 2: V column sums, two stages.
// ============================================================
__global__ __launch_bounds__(256) void vsum1_kernel(
    const float* __restrict__ v_ws, float* __restrict__ part)
{
    __shared__ float red[4][HD];
    const int bh = blockIdx.x, sl = blockIdx.y;
    const int d = threadIdx.x & 63, sub = threadIdx.x >> 6;
    const float* vh = v_ws + ((size_t)bh << 16) + ((size_t)(sl*128 + sub*32) << 6);
    float s = 0.f;
    #pragma unroll 4
    for (int m = 0; m < 32; m++) s += vh[(m << 6) + d];
    red[sub][d] = s;
    __syncthreads();
    if (threadIdx.x < HD)
        part[((size_t)bh*8 + sl)*HD + d] = red[0][d]+red[1][d]+red[2][d]+red[3][d];
}

__global__ __launch_bounds__(256) void vsum2_kernel(
    const float* __restrict__ part, float* __restrict__ vs)
{
    const int bh = blockIdx.x*4 + (threadIdx.x >> 6), d = threadIdx.x & 63;
    float s = 0.f;
    #pragma unroll
    for (int i = 0; i < 8; i++) s += part[((size_t)bh*8 + i)*HD + d];
    vs[(bh << 6) + d] = s;
}

// ============================================================
// Kernel 3: FUSED scores + top-16 + sparse softmax + PV, LDS pane.
// Block = (bh, 16 rows); 4 waves each compute a 256-col quarter of
// the 16x1024 fp32 score pane into LDS (exact values -> exact topk).
// One barrier. Extraction: wave w owns rows w*4..+3; lane l owns cols
// {j*64+l} -> conflict-free lane-consecutive LDS reads; 16 rounds of
// wave-argmax (value desc, col asc = exact jax.lax.top_k order);
// softmax + PV + bf16 split write. 64 KB LDS -> 2 blocks/CU (phases
// of co-resident blocks overlap). grid x = bh pins K/V per XCD L2.
// ============================================================
__global__ __launch_bounds__(256) void attn_fused_kernel(
    const u16* __restrict__ qhi_g, const u16* __restrict__ qlo_g,
    const u16* __restrict__ khi_g, const u16* __restrict__ klo_g,
    const float* __restrict__ v_ws, const float* __restrict__ vsum_ws,
    u16* __restrict__ aohi, u16* __restrict__ aolo)
{
    __shared__ float s_lds[16 * 1024];    // 65536 B

    const int bh = blockIdx.x;            // 0..63
    const int nb = blockIdx.y;            // 0..63 (16-row block)
    const int tid = threadIdx.x, lane = tid & 63, w = tid >> 6;
    const int l15 = lane & 15, l4 = lane >> 4;
    const size_t hb = (size_t)bh << 16;   // * SEQ*HD
    const int n0 = nb * 16;

    // Q fragments for rows n0..n0+15 (same for all waves)
    bf16x8 qh[2], ql[2];
    {
        const size_t qoff = hb + (size_t)(n0 + l15) * HD + l4 * 8;
        qh[0] = *(const bf16x8*)(qhi_g + qoff);
        qh[1] = *(const bf16x8*)(qhi_g + qoff + 32);
        ql[0] = *(const bf16x8*)(qlo_g + qoff);
        ql[1] = *(const bf16x8*)(qlo_g + qoff + 32);
    }

    // ---- score phase: wave w covers cols w*256 .. w*256+255 ----
    const int rwb = l4 * 4;               // C-layout row base (0..12)
    #pragma unroll 2
    for (int T = 0; T < 16; T++) {
        const int col16 = w * 256 + T * 16;
        const size_t koff = hb + (size_t)(col16 + l15) * HD + l4 * 8;
        bf16x8 kh0 = *(const bf16x8*)(khi_g + koff);
        bf16x8 kh1 = *(const bf16x8*)(khi_g + koff + 32);
        bf16x8 kl0 = *(const bf16x8*)(klo_g + koff);
        bf16x8 kl1 = *(const bf16x8*)(klo_g + koff + 32);
        f32x4v acc = {0.f, 0.f, 0.f, 0.f};
        acc = MFMA16(qh[0], kh0, acc);
        acc = MFMA16(qh[0], kl0, acc);
        acc = MFMA16(ql[0], kh0, acc);
        acc = MFMA16(qh[1], kh1, acc);
        acc = MFMA16(qh[1], kl1, acc);
        acc = MFMA16(ql[1], kh1, acc);
        // C/D: col = col16+l15, rows rwb..rwb+3
        float* sp = &s_lds[rwb * 1024 + col16 + l15];
        sp[0 * 1024] = acc[0];
        sp[1 * 1024] = acc[1];
        sp[2 * 1024] = acc[2];
        sp[3 * 1024] = acc[3];
    }
    __syncthreads();

    // ---- extraction phase: wave w owns rows w*4 .. w*4+3 ----
    const float* vh = v_ws + hb;
    const float vs = vsum_ws[(bh << 6) + lane];
    #pragma unroll 1
    for (int rr = 0; rr < 4; rr++) {
        const int rl = w * 4 + rr;
        const int n = n0 + rl;
        float v[16];
        #pragma unroll
        for (int j = 0; j < 16; j++) v[j] = s_lds[rl * 1024 + j * 64 + lane];

        float mv[TOPK]; int mi[TOPK];
        #pragma unroll
        for (int t = 0; t < TOPK; t++) {
            float bv = v[0]; int bj = 0;
            #pragma unroll
            for (int j = 1; j < 16; j++) { if (v[j] > bv) { bv = v[j]; bj = j; } }
            int bc = bj * 64 + lane;
            #pragma unroll
            for (int off = 32; off; off >>= 1) {
                float ov = __shfl_xor(bv, off);
                int   oc = __shfl_xor(bc, off);
                if (ov > bv || (ov == bv && oc < bc)) { bv = ov; bc = oc; }
            }
            mv[t] = bv; mi[t] = bc;
            int jj = ((bc & 63) == lane) ? (bc >> 6) : -1;
            #pragma unroll
            for (int j = 0; j < 16; j++) { if (j == jj) v[j] = -FLT_MAX; }
        }

        float mx = fmaxf(mv[0], 0.f);
        float e  = expf(-mx);
        float Z  = (float)(SEQ - TOPK) * e;
        float wexp[TOPK];
        #pragma unroll
        for (int t = 0; t < TOPK; t++) { wexp[t] = expf(mv[t] - mx); Z += wexp[t]; }
        float invZ = 1.f / Z;
        float acc = (e * invZ) * vs;
        #pragma unroll
        for (int t = 0; t < TOPK; t++)
            acc = fmaf((wexp[t] - e) * invZ, vh[((size_t)mi[t] << 6) + lane], acc);

        u16 oh, ol; bf16split(acc, oh, ol);
        size_t oidx = (((size_t)(bh >> 3) << 10) + n) * CDIM + ((bh & 7) << 6) + lane;
        aohi[oidx] = oh; aolo[oidx] = ol;
    }
}

// ============================================================
// Kernel 4: output projection, split-bf16 MFMA, ZERO LDS / barriers.
// Block = 64 rows x 64 cols; wave = 16 x 64. Grid (128,8) = 1024
// blocks = 4/CU.
// ============================================================
__global__ __launch_bounds__(256) void proj_mfma_kernel(
    const u16* __restrict__ apl,      // [2][8192][512]
    const u16* __restrict__ wppl,     // [2][512][512]
    const float* __restrict__ bp, float* __restrict__ out)
{
    const int tid = threadIdx.x, lane = tid & 63, w = tid >> 6;
    const int l15 = lane & 15, l4 = lane >> 4;
    const int row0 = blockIdx.x * 64 + w * 16;
    const int c0   = blockIdx.y * 64;

    f32x4v acc[4];
    #pragma unroll
    for (int nt = 0; nt < 4; nt++) acc[nt] = (f32x4v){0.f,0.f,0.f,0.f};

    const u16* aph = apl  + (size_t)(row0 + l15) * 512 + l4 * 8;
    const u16* bph = wppl + (size_t)(c0   + l15) * 512 + l4 * 8;

    #pragma unroll 2
    for (int kc = 0; kc < 16; kc++) {
        const int ko = kc * 32;
        bf16x8 ah = *(const bf16x8*)(aph + ko);
        bf16x8 al = *(const bf16x8*)(aph + XPLANE + ko);
        #pragma unroll
        for (int nt = 0; nt < 4; nt++) {
            bf16x8 bh_ = *(const bf16x8*)(bph + nt*16*512 + ko);
            bf16x8 bl_ = *(const bf16x8*)(bph + WPPLANE + nt*16*512 + ko);
            acc[nt] = MFMA16(ah, bh_, acc[nt]);
            acc[nt] = MFMA16(ah, bl_, acc[nt]);
            acc[nt] = MFMA16(al, bh_, acc[nt]);
        }
    }

    const int rbase = row0 + l4 * 4;
    #pragma unroll
    for (int nt = 0; nt < 4; nt++) {
        const int cg = c0 + nt*16 + l15;
        const float bias = bp[cg];
        #pragma unroll
        for (int rg = 0; rg < 4; rg++) {
            int r = rbase + rg;
            out[(size_t)r * CDIM + cg] = acc[nt][rg] + bias;
        }
    }
}

// ============================================================
extern "C" void kernel_launch(void* const* d_in, const int* in_sizes, int n_in,
                              void* d_out, int out_size, void* d_ws, size_t ws_size,
                              hipStream_t stream)
{
    const float* x   = (const float*)d_in[0];
    const float* Wq  = (const float*)d_in[1];
    const float* bq  = (const float*)d_in[2];
    const float* Wkv = (const float*)d_in[3];
    const float* bkv = (const float*)d_in[4];
    const float* Wp  = (const float*)d_in[5];
    const float* bp  = (const float*)d_in[6];
    float* out = (float*)d_out;

    // workspace layout
    float* ws    = (float*)d_ws;
    float* v_ws  = ws;                               // HSZ fl
    float* vs_ws = v_ws + HSZ;                       // 4096 fl
    float* vp_ws = vs_ws + 4096;                     // 32768 fl (vsum partials)
    u16* qhi_g = (u16*)(vp_ws + 32768);
    u16* qlo_g = qhi_g + HSZ;
    u16* khi_g = qhi_g + 2 * HSZ;
    u16* klo_g = qhi_g + 3 * HSZ;
    u16* xpl   = qhi_g + 4 * HSZ;                    // 2 planes
    u16* wtpl  = xpl + 2 * XPLANE;                   // 2 planes
    u16* wppl  = wtpl + 2 * WTPLANE;                 // 2 planes
    u16* aohi  = wppl + 2 * WPPLANE;
    u16* aolo  = aohi + XPLANE;

    split_f32_kernel<<<(int)((XPLANE/4 + 255)/256), 256, 0, stream>>>(
        x, xpl, xpl + XPLANE, (int)(XPLANE/4));
    tsplit_kernel<<<dim3(8, 8),  256, 0, stream>>>(Wq,  512,  wtpl, wtpl + WTPLANE);
    tsplit_kernel<<<dim3(16, 8), 256, 0, stream>>>(Wkv, 1024, wtpl + (size_t)512*512,
                                                   wtpl + WTPLANE + (size_t)512*512);
    tsplit_kernel<<<dim3(8, 8),  256, 0, stream>>>(Wp,  512,  wppl, wppl + WPPLANE);

    qkv_mfma_kernel<<<dim3(64, 24), 256, 0, stream>>>(
        xpl, wtpl, bq, bkv, qhi_g, qlo_g, khi_g, klo_g, v_ws);
    vsum1_kernel<<<dim3(BATCH * HEADS, 8), 256, 0, stream>>>(v_ws, vp_ws);
    vsum2_kernel<<<16, 256, 0, stream>>>(vp_ws, vs_ws);
    attn_fused_kernel<<<dim3(BATCH * HEADS, SEQ / 16), 256, 0, stream>>>(
        qhi_g, qlo_g, khi_g, klo_g, v_ws, vs_ws, aohi, aolo);
    proj_mfma_kernel<<<dim3(128, 8), 256, 0, stream>>>(aohi, wppl, bp, out);
}